// Round 9
// baseline (164.487 us; speedup 1.0000x reference)
//
#include <hip/hip_runtime.h>
#include <hip/hip_bf16.h>

#define N_NODES 100000
#define E_EDGES 1600000
#define DIN 256
#define C_OUT 64
#define NID_CNT 10000
#define NEG 0.2f
#define NBUCK 391   // ceil(N_NODES/256) coarse buckets (dst >> 8)
#define NBINBLK 391 // ceil(E_EDGES/4096)
#define GEMM_BLOCKS 782  // ceil(100000/128)
#define ID_BLOCKS 79     // ceil(10000/128)

typedef short bf16x8 __attribute__((ext_vector_type(8)));
typedef float f32x4  __attribute__((ext_vector_type(4)));

__device__ __forceinline__ float lrelu(float x) { return x > 0.f ? x : NEG * x; }
__device__ __forceinline__ unsigned short f2bs(float f) {
    __hip_bfloat16 b = __float2bfloat16(f);
    return *reinterpret_cast<unsigned short*>(&b);
}
__device__ __forceinline__ bf16x8 pack8(float4 a, float4 b) {
    bf16x8 r;
    r[0] = (short)f2bs(a.x); r[1] = (short)f2bs(a.y);
    r[2] = (short)f2bs(a.z); r[3] = (short)f2bs(a.w);
    r[4] = (short)f2bs(b.x); r[5] = (short)f2bs(b.y);
    r[6] = (short)f2bs(b.z); r[7] = (short)f2bs(b.w);
    return r;
}
__device__ __forceinline__ float2 unpk2(unsigned u) {
    return make_float2(__uint_as_float(u << 16), __uint_as_float(u & 0xffff0000u));
}

// ---------------- zero scratch ----------------
__global__ __launch_bounds__(256) void k_zero(float* __restrict__ cnt,
                                              int* __restrict__ bkcnt,
                                              int* __restrict__ ucnt) {
    const int t = blockIdx.x * 256 + threadIdx.x;
    if (t < N_NODES) cnt[t] = 0.f;
    if (t <= NBUCK) bkcnt[t] = 0;
    if (t == 0) *ucnt = 0;
}

// ---------------- merged prep: W/Wid cvt+transpose | id multiplicity | bucket hist ----------------
__global__ __launch_bounds__(256) void k_prep(const float* __restrict__ W,
                                              const float* __restrict__ Wid,
                                              unsigned short* __restrict__ WtG,
                                              unsigned short* __restrict__ WidtG,
                                              const int* __restrict__ nid,
                                              float* __restrict__ cnt,
                                              const int* __restrict__ ei,
                                              int* __restrict__ bkcnt) {
    __shared__ int lcnt[NBUCK];
    const int b = blockIdx.x;
    const int tid = threadIdx.x;
    if (b < 128) {                       // cvt: 32768 elements
        const int t = b * 256 + tid;
        const int mat = t >> 14;
        const int r = t & 16383;
        const int k = r >> 6, c = r & 63;
        if (mat == 0) WtG[c * DIN + k] = f2bs(W[(long)k * C_OUT + c]);
        else          WidtG[c * DIN + k] = f2bs(Wid[(long)k * C_OUT + c]);
    } else if (b < 168) {                // cnt: 10000 ids
        const int t = (b - 128) * 256 + tid;
        if (t < NID_CNT) atomicAdd(&cnt[nid[t]], 1.0f);
    } else {                             // bhist
        for (int i = tid; i < NBUCK; i += 256) lcnt[i] = 0;
        __syncthreads();
        const int e0 = (b - 168) * 4096;
        #pragma unroll
        for (int j = 0; j < 16; ++j) {
            int e = e0 + j * 256 + tid;
            if (e < E_EDGES) atomicAdd(&lcnt[ei[E_EDGES + e] >> 8], 1);
        }
        __syncthreads();
        for (int i = tid; i < NBUCK; i += 256)
            if (lcnt[i]) atomicAdd(&bkcnt[i], lcnt[i]);
    }
}

// ---------------- bucket scan (block 0) + id-unique list build (other blocks) ----------------
__global__ __launch_bounds__(512) void k_bscan(const int* __restrict__ bkcnt,
                                               int* __restrict__ bkoff,
                                               int* __restrict__ bkcur,
                                               const float* __restrict__ cnt,
                                               int* __restrict__ ulist,
                                               int* __restrict__ ucnt) {
    const int tid = threadIdx.x;
    if (blockIdx.x == 0) {
        __shared__ int tmp[512];
        const int v = (tid < NBUCK) ? bkcnt[tid] : 0;
        tmp[tid] = v;
        __syncthreads();
        for (int o = 1; o < 512; o <<= 1) {
            int t = (tid >= o) ? tmp[tid - o] : 0;
            __syncthreads();
            tmp[tid] += t;
            __syncthreads();
        }
        if (tid < NBUCK) {
            int excl = tmp[tid] - v;
            bkoff[tid] = excl;
            bkcur[tid] = excl;
            if (tid == NBUCK - 1) bkoff[NBUCK] = tmp[tid];
        }
    } else {
        const int n = (blockIdx.x - 1) * 512 + tid;
        if (n < N_NODES && cnt[n] > 0.5f) {
            int p = atomicAdd(ucnt, 1);
            ulist[p] = n;
        }
    }
}

__global__ __launch_bounds__(256) void k_bin(const int* __restrict__ ei,
                                             int* __restrict__ bkcur,
                                             int2* __restrict__ binned) {
    __shared__ int cnt[NBUCK];
    __shared__ int base[NBUCK];
    __shared__ int lcur[NBUCK];
    const int tid = threadIdx.x;
    for (int i = tid; i < NBUCK; i += 256) cnt[i] = 0;
    __syncthreads();
    const int e0 = blockIdx.x * 4096;
    int s[16], d[16];
    #pragma unroll
    for (int j = 0; j < 16; ++j) {
        int e = e0 + j * 256 + tid;
        if (e < E_EDGES) {
            s[j] = ei[e];
            d[j] = ei[E_EDGES + e];
            atomicAdd(&cnt[d[j] >> 8], 1);
        } else d[j] = -1;
    }
    __syncthreads();
    for (int i = tid; i < NBUCK; i += 256) {
        base[i] = cnt[i] ? atomicAdd(&bkcur[i], cnt[i]) : 0;
        lcur[i] = 0;
    }
    __syncthreads();
    #pragma unroll
    for (int j = 0; j < 16; ++j) {
        if (d[j] >= 0) {
            int b = d[j] >> 8;
            int r = atomicAdd(&lcur[b], 1);
            binned[base[b] + r] = make_int2(s[j], d[j]);
        }
    }
}

__global__ __launch_bounds__(256) void k_place(const int2* __restrict__ binned,
                                               const int* __restrict__ bkoff,
                                               int* __restrict__ csr,
                                               int* __restrict__ cur) {
    __shared__ int ncnt[256];
    __shared__ int tmp[256];
    __shared__ int ncur[256];
    const int tid = threadIdx.x;
    const int b = blockIdx.x;
    const int lo = bkoff[b], hi = bkoff[b + 1];
    const int node0 = b << 8;
    ncnt[tid] = 0;
    __syncthreads();
    for (int e = lo + tid; e < hi; e += 256)
        atomicAdd(&ncnt[binned[e].y - node0], 1);
    __syncthreads();
    const int v = ncnt[tid];
    tmp[tid] = v;
    __syncthreads();
    for (int o = 1; o < 256; o <<= 1) {
        int t = (tid >= o) ? tmp[tid - o] : 0;
        __syncthreads();
        tmp[tid] += t;
        __syncthreads();
    }
    const int incl = tmp[tid];
    if (node0 + tid < N_NODES) cur[node0 + tid] = lo + incl;  // inclusive end
    ncur[tid] = incl - v;
    __syncthreads();
    for (int e = lo + tid; e < hi; e += 256) {
        int2 p = binned[e];
        int r = atomicAdd(&ncur[p.y - node0], 1);
        csr[lo + r] = p.x;
    }
}

// ---------------- main MFMA GEMM: h = x@W only; emits hb, ad, as ----------------
// 256 thr = 4 waves x 32 rows = 128 rows/block; W^T in 32KB LDS (swizzled);
// depth-3 register prefetch of x keeps ~8 float4/wave in flight; 3 blocks/CU.
__global__ __launch_bounds__(256, 3) void k_gemm_fused(const float* __restrict__ x,
                                                       const unsigned short* __restrict__ WtG,
                                                       const float* __restrict__ att,
                                                       __hip_bfloat16* __restrict__ hb,
                                                       float* __restrict__ ad,
                                                       float* __restrict__ as) {
    __shared__ __align__(16) char wlds[32768];  // Wt [64c][512B] swz; epilogue: hb tile [128][128B]
    const int tid = threadIdx.x;
    const int w = tid >> 6, l = tid & 63;
    const int g = l >> 4, cl = l & 15;
    const int r0 = blockIdx.x * 128;

    #pragma unroll
    for (int i = 0; i < 8; ++i) {
        int f = tid + i * 256;     // 2048 chunks of 16B
        int c = f >> 5, s = f & 31;
        int byte = c * 512 + ((s ^ (c & 7)) << 4);
        *(bf16x8*)(wlds + byte) = *(const bf16x8*)(WtG + (long)c * DIN + s * 8);
    }
    __syncthreads();

    f32x4 acc[2][4] = {};
    const int row0 = r0 + w * 32 + cl;
    const float* xp0 = x + (long)min(row0, N_NODES - 1) * DIN + g * 8;
    const float* xp1 = x + (long)min(row0 + 16, N_NODES - 1) * DIN + g * 8;

    float4 xb[3][4];
    #pragma unroll
    for (int p = 0; p < 2; ++p) {
        xb[p][0] = *(const float4*)(xp0 + p * 32);
        xb[p][1] = *(const float4*)(xp0 + p * 32 + 4);
        xb[p][2] = *(const float4*)(xp1 + p * 32);
        xb[p][3] = *(const float4*)(xp1 + p * 32 + 4);
    }
    #pragma unroll
    for (int kt = 0; kt < 8; ++kt) {
        const int st = kt % 3;
        if (kt + 2 < 8) {
            const int ps = (kt + 2) % 3;
            xb[ps][0] = *(const float4*)(xp0 + (kt + 2) * 32);
            xb[ps][1] = *(const float4*)(xp0 + (kt + 2) * 32 + 4);
            xb[ps][2] = *(const float4*)(xp1 + (kt + 2) * 32);
            xb[ps][3] = *(const float4*)(xp1 + (kt + 2) * 32 + 4);
        }
        bf16x8 a0 = pack8(xb[st][0], xb[st][1]);
        bf16x8 a1 = pack8(xb[st][2], xb[st][3]);
        #pragma unroll
        for (int ct = 0; ct < 4; ++ct) {
            int c = ct * 16 + cl;
            int byte = c * 512 + (((kt * 4 + g) ^ (c & 7)) << 4);
            bf16x8 bw = *(const bf16x8*)(wlds + byte);
            acc[0][ct] = __builtin_amdgcn_mfma_f32_16x16x32_bf16(a0, bw, acc[0][ct], 0, 0, 0);
            acc[1][ct] = __builtin_amdgcn_mfma_f32_16x16x32_bf16(a1, bw, acc[1][ct], 0, 0, 0);
        }
    }
    __syncthreads();  // wlds free for epilogue tile

    float attv1[4], attv2[4];
    #pragma unroll
    for (int ct = 0; ct < 4; ++ct) {
        attv1[ct] = att[ct * 16 + cl];
        attv2[ct] = att[C_OUT + ct * 16 + cl];
    }
    unsigned short* hbt = (unsigned short*)wlds;
    #pragma unroll
    for (int rt = 0; rt < 2; ++rt) {
        #pragma unroll
        for (int reg = 0; reg < 4; ++reg) {
            const int rbl = w * 32 + rt * 16 + g * 4 + reg;  // 0..127
            float pd = 0.f, ps = 0.f;
            #pragma unroll
            for (int ct = 0; ct < 4; ++ct) {
                float hv = acc[rt][ct][reg];
                pd += hv * attv1[ct];
                ps += hv * attv2[ct];
                const int col = ct * 16 + cl;
                const int slot = (col >> 3) ^ (rbl & 7);
                hbt[rbl * 64 + slot * 8 + (col & 7)] = f2bs(hv);
            }
            #pragma unroll
            for (int o = 1; o < 16; o <<= 1) {
                pd += __shfl_xor(pd, o, 64);
                ps += __shfl_xor(ps, o, 64);
            }
            if (cl == 0) {
                int grow = r0 + rbl;
                if (grow < N_NODES) { ad[grow] = pd; as[grow] = ps; }
            }
        }
    }
    __syncthreads();
    #pragma unroll
    for (int i = 0; i < 4; ++i) {
        int f = tid + i * 256;
        int row = f >> 3, s = f & 7;
        int grow = r0 + row;
        if (grow < N_NODES) {
            bf16x8 v = *(const bf16x8*)(wlds + row * 128 + ((s ^ (row & 7)) << 4));
            *(bf16x8*)((unsigned short*)hb + (long)grow * C_OUT + s * 8) = v;
        }
    }
}

// ---------------- id fix-up GEMM: for unique id rows, recompute h = x@W + cnt*(x@Wid) ----------------
__global__ __launch_bounds__(256) void k_gemm_id(const float* __restrict__ x,
                                                 const unsigned short* __restrict__ WtG,
                                                 const unsigned short* __restrict__ WidtG,
                                                 const float* __restrict__ cnt,
                                                 const int* __restrict__ ulist,
                                                 const int* __restrict__ ucnt,
                                                 const float* __restrict__ att,
                                                 __hip_bfloat16* __restrict__ hb,
                                                 float* __restrict__ ad,
                                                 float* __restrict__ as) {
    __shared__ __align__(16) char wlds[65536];  // Wt | Wid (32KB each), swizzled
    __shared__ int nodes[128];
    __shared__ float cvs[128];
    const int tid = threadIdx.x;
    const int w = tid >> 6, l = tid & 63;
    const int g = l >> 4, cl = l & 15;
    const int r0 = blockIdx.x * 128;
    const int U = *ucnt;
    if (tid < 128) {
        int idx = r0 + tid;
        int nd = (idx < U) ? ulist[idx] : -1;
        nodes[tid] = nd;
        cvs[tid] = (nd >= 0) ? cnt[nd] : 0.f;
    }
    #pragma unroll
    for (int i = 0; i < 16; ++i) {
        int f = tid + i * 256;     // 4096 chunks of 16B
        int half = f >> 11;
        int ff = f & 2047;
        int c = ff >> 5, s = ff & 31;
        int byte = half * 32768 + c * 512 + ((s ^ (c & 7)) << 4);
        const unsigned short* src = half ? WidtG : WtG;
        *(bf16x8*)(wlds + byte) = *(const bf16x8*)(src + (long)c * DIN + s * 8);
    }
    __syncthreads();

    const int n0 = nodes[w * 32 + cl];
    const int n1 = nodes[w * 32 + 16 + cl];
    const float* xp0 = x + (long)max(n0, 0) * DIN + g * 8;
    const float* xp1 = x + (long)max(n1, 0) * DIN + g * 8;

    f32x4 acc1[2][4] = {};
    f32x4 acc2[2][4] = {};
    #pragma unroll
    for (int kt = 0; kt < 8; ++kt) {
        float4 u0 = *(const float4*)(xp0 + kt * 32);
        float4 u1 = *(const float4*)(xp0 + kt * 32 + 4);
        float4 v0 = *(const float4*)(xp1 + kt * 32);
        float4 v1 = *(const float4*)(xp1 + kt * 32 + 4);
        bf16x8 a0 = pack8(u0, u1);
        bf16x8 a1 = pack8(v0, v1);
        #pragma unroll
        for (int ct = 0; ct < 4; ++ct) {
            int c = ct * 16 + cl;
            int byte = c * 512 + (((kt * 4 + g) ^ (c & 7)) << 4);
            bf16x8 bw = *(const bf16x8*)(wlds + byte);
            bf16x8 bi = *(const bf16x8*)(wlds + 32768 + byte);
            acc1[0][ct] = __builtin_amdgcn_mfma_f32_16x16x32_bf16(a0, bw, acc1[0][ct], 0, 0, 0);
            acc1[1][ct] = __builtin_amdgcn_mfma_f32_16x16x32_bf16(a1, bw, acc1[1][ct], 0, 0, 0);
            acc2[0][ct] = __builtin_amdgcn_mfma_f32_16x16x32_bf16(a0, bi, acc2[0][ct], 0, 0, 0);
            acc2[1][ct] = __builtin_amdgcn_mfma_f32_16x16x32_bf16(a1, bi, acc2[1][ct], 0, 0, 0);
        }
    }
    __syncthreads();

    float attv1[4], attv2[4];
    #pragma unroll
    for (int ct = 0; ct < 4; ++ct) {
        attv1[ct] = att[ct * 16 + cl];
        attv2[ct] = att[C_OUT + ct * 16 + cl];
    }
    unsigned short* hbt = (unsigned short*)wlds;
    #pragma unroll
    for (int rt = 0; rt < 2; ++rt) {
        #pragma unroll
        for (int reg = 0; reg < 4; ++reg) {
            const int rbl = w * 32 + rt * 16 + g * 4 + reg;
            const float cv = cvs[rbl];
            float pd = 0.f, ps = 0.f;
            #pragma unroll
            for (int ct = 0; ct < 4; ++ct) {
                float hv = acc1[rt][ct][reg] + cv * acc2[rt][ct][reg];
                pd += hv * attv1[ct];
                ps += hv * attv2[ct];
                const int col = ct * 16 + cl;
                const int slot = (col >> 3) ^ (rbl & 7);
                hbt[rbl * 64 + slot * 8 + (col & 7)] = f2bs(hv);
            }
            #pragma unroll
            for (int o = 1; o < 16; o <<= 1) {
                pd += __shfl_xor(pd, o, 64);
                ps += __shfl_xor(ps, o, 64);
            }
            if (cl == 0) {
                int nd = nodes[rbl];
                if (nd >= 0) { ad[nd] = pd; as[nd] = ps; }
            }
        }
    }
    __syncthreads();
    #pragma unroll
    for (int i = 0; i < 4; ++i) {
        int f = tid + i * 256;
        int row = f >> 3, s = f & 7;
        int nd = nodes[row];
        if (nd >= 0) {
            bf16x8 v = *(const bf16x8*)(wlds + row * 128 + ((s ^ (row & 7)) << 4));
            *(bf16x8*)((unsigned short*)hb + (long)nd * C_OUT + s * 8) = v;
        }
    }
}

// ---------------- gather: 2 nodes/wave (32-lane groups), 2 channels/lane (bf16x2) ----------------
__global__ __launch_bounds__(256) void k_gather(const int* __restrict__ cur,
                                                const int* __restrict__ csr,
                                                const unsigned* __restrict__ hb2,
                                                const float* __restrict__ ad,
                                                const float* __restrict__ as,
                                                float* __restrict__ out) {
    const int lane = threadIdx.x & 63;
    const int lg = lane & 31;
    const int gb = lane & 32;
    const int i = blockIdx.x * 8 + ((threadIdx.x >> 6) << 1) + (lane >> 5);
    if (i >= N_NODES) return;
    const int end   = cur[i];
    const int start = (i > 0) ? cur[i - 1] : 0;
    const int deg   = end - start;
    const float adi = ad[i];
    const float asi = as[i];
    float2 acc;
    float den;
    if (deg <= 32) {
        int s = 0; float a = -1e30f;
        if (lg < deg) { s = csr[start + lg]; a = as[s]; }
        float mx = fmaxf(a, asi);
        #pragma unroll
        for (int o = 16; o > 0; o >>= 1) mx = fmaxf(mx, __shfl_xor(mx, o, 64));
        const float m = lrelu(adi + mx);
        float w = (lg < deg) ? __expf(lrelu(adi + a) - m) : 0.f;
        const float wself = __expf(lrelu(adi + asi) - m);
        float wsum = w;
        #pragma unroll
        for (int o = 16; o > 0; o >>= 1) wsum += __shfl_xor(wsum, o, 64);
        den = wself + wsum;
        float2 hv = unpk2(hb2[(long)i * 32 + lg]);
        acc = make_float2(wself * hv.x, wself * hv.y);
        int j = 0;
        for (; j + 4 <= deg; j += 4) {
            int   s0 = __shfl(s, gb + j, 64),     s1 = __shfl(s, gb + j + 1, 64),
                  s2 = __shfl(s, gb + j + 2, 64), s3 = __shfl(s, gb + j + 3, 64);
            float w0 = __shfl(w, gb + j, 64),     w1 = __shfl(w, gb + j + 1, 64),
                  w2 = __shfl(w, gb + j + 2, 64), w3 = __shfl(w, gb + j + 3, 64);
            float2 h0 = unpk2(hb2[(long)s0 * 32 + lg]);
            float2 h1 = unpk2(hb2[(long)s1 * 32 + lg]);
            float2 h2 = unpk2(hb2[(long)s2 * 32 + lg]);
            float2 h3 = unpk2(hb2[(long)s3 * 32 + lg]);
            acc.x += w0 * h0.x; acc.y += w0 * h0.y;
            acc.x += w1 * h1.x; acc.y += w1 * h1.y;
            acc.x += w2 * h2.x; acc.y += w2 * h2.y;
            acc.x += w3 * h3.x; acc.y += w3 * h3.y;
        }
        for (; j < deg; ++j) {
            int   sj = __shfl(s, gb + j, 64);
            float wj = __shfl(w, gb + j, 64);
            float2 hj = unpk2(hb2[(long)sj * 32 + lg]);
            acc.x += wj * hj.x; acc.y += wj * hj.y;
        }
    } else {
        float mx = asi;
        for (int b = 0; b < deg; b += 32) {
            int idx = b + lg;
            if (idx < deg) mx = fmaxf(mx, as[csr[start + idx]]);
        }
        #pragma unroll
        for (int o = 16; o > 0; o >>= 1) mx = fmaxf(mx, __shfl_xor(mx, o, 64));
        const float m = lrelu(adi + mx);
        const float wself = __expf(lrelu(adi + asi) - m);
        float2 hv = unpk2(hb2[(long)i * 32 + lg]);
        acc = make_float2(wself * hv.x, wself * hv.y);
        den = wself;
        for (int b = 0; b < deg; b += 32) {
            int idx = b + lg;
            int s = 0; float w = 0.f;
            if (idx < deg) {
                s = csr[start + idx];
                w = __expf(lrelu(adi + as[s]) - m);
            }
            const int cnt2 = min(32, deg - b);
            for (int j = 0; j < cnt2; ++j) {
                int   sj = __shfl(s, gb + j, 64);
                float wj = __shfl(w, gb + j, 64);
                float2 hj = unpk2(hb2[(long)sj * 32 + lg]);
                acc.x += wj * hj.x; acc.y += wj * hj.y;
            }
            float wsum = w;
            #pragma unroll
            for (int o = 16; o > 0; o >>= 1) wsum += __shfl_xor(wsum, o, 64);
            den += wsum;
        }
    }
    const float r = 1.f / (den + 1e-16f);
    *(float2*)(out + (long)i * C_OUT + lg * 2) = make_float2(acc.x * r, acc.y * r);
}

extern "C" void kernel_launch(void* const* d_in, const int* in_sizes, int n_in,
                              void* d_out, int out_size, void* d_ws, size_t ws_size,
                              hipStream_t stream) {
    const float* x   = (const float*)d_in[0];
    const int*   ei  = (const int*)d_in[1];
    const int*   nid = (const int*)d_in[2];
    const float* W   = (const float*)d_in[3];
    const float* Wid = (const float*)d_in[4];
    const float* att = (const float*)d_in[5];
    float* out = (float*)d_out;

    char* ws = (char*)d_ws;
    __hip_bfloat16* hb = (__hip_bfloat16*)(ws);      // 12,800,000 B
    int2*  binned = (int2*)(ws);                     // aliases hb; CSR phase only (before gemm)
    float* ad    = (float*)(ws + 12800000);          //    400,000 B
    float* as    = (float*)(ws + 13200000);          //    400,000 B
    int*   cur   = (int*)  (ws + 13600000);          //    400,000 B
    float* cnt   = (float*)(ws + 14000000);          //    400,000 B
    int*   csr   = (int*)  (ws + 14400000);          //  6,400,000 B
    unsigned short* WtG  = (unsigned short*)(ws + 20800000);  // 32,768 B
    unsigned short* WidG = (unsigned short*)(ws + 20832768);  // 32,768 B
    int*   bkcnt = (int*)  (ws + 20865536);          //  1,600 B
    int*   bkoff = (int*)  (ws + 20867200);          //  1,600 B
    int*   bkcur = (int*)  (ws + 20868800);          //  1,600 B
    int*   ulist = (int*)  (ws + 20870400);          //  40,000 B
    int*   ucnt  = (int*)  (ws + 20910400);          //  64 B

    k_zero<<<393, 256, 0, stream>>>(cnt, bkcnt, ucnt);
    k_prep<<<559, 256, 0, stream>>>(W, Wid, WtG, WidG, nid, cnt, ei, bkcnt);
    k_bscan<<<197, 512, 0, stream>>>(bkcnt, bkoff, bkcur, cnt, ulist, ucnt);
    k_bin<<<NBINBLK, 256, 0, stream>>>(ei, bkcur, binned);
    k_place<<<NBUCK, 256, 0, stream>>>(binned, bkoff, csr, cur);
    // feature path: main GEMM (x@W) then id fix-up rows
    k_gemm_fused<<<GEMM_BLOCKS, 256, 0, stream>>>(x, WtG, att, hb, ad, as);
    k_gemm_id<<<ID_BLOCKS, 256, 0, stream>>>(x, WtG, WidG, cnt, ulist, ucnt, att, hb, ad, as);
    k_gather<<<12500, 256, 0, stream>>>(cur, csr, (const unsigned*)hb, ad, as, out);
}

// Round 11
// 138.276 us; speedup vs baseline: 1.1896x; 1.1896x over previous
//
#include <hip/hip_runtime.h>
#include <hip/hip_bf16.h>

#define N_NODES 100000
#define E_EDGES 1600000
#define DIN 256
#define C_OUT 64
#define NID_CNT 10000
#define NEG 0.2f
#define NBUCK 391   // ceil(N_NODES/256) coarse buckets (dst >> 8)
#define NBINBLK 391 // ceil(E_EDGES/4096)
#define GEMM_BLOCKS 391  // ceil(100000/256)

typedef short bf16x8 __attribute__((ext_vector_type(8)));
typedef float f32x4  __attribute__((ext_vector_type(4)));

__device__ __forceinline__ float lrelu(float x) { return x > 0.f ? x : NEG * x; }
__device__ __forceinline__ unsigned short f2bs(float f) {
    __hip_bfloat16 b = __float2bfloat16(f);
    return *reinterpret_cast<unsigned short*>(&b);
}
__device__ __forceinline__ bf16x8 pack8(float4 a, float4 b) {
    bf16x8 r;
    r[0] = (short)f2bs(a.x); r[1] = (short)f2bs(a.y);
    r[2] = (short)f2bs(a.z); r[3] = (short)f2bs(a.w);
    r[4] = (short)f2bs(b.x); r[5] = (short)f2bs(b.y);
    r[6] = (short)f2bs(b.z); r[7] = (short)f2bs(b.w);
    return r;
}
// bf16x2 (packed in u32) -> two floats
__device__ __forceinline__ float2 unpk2(unsigned u) {
    return make_float2(__uint_as_float(u << 16), __uint_as_float(u & 0xffff0000u));
}

// ---------------- zero scratch (replaces memsets) ----------------
__global__ __launch_bounds__(256) void k_zero(float* __restrict__ cnt,
                                              int* __restrict__ bkcnt) {
    const int t = blockIdx.x * 256 + threadIdx.x;
    if (t < N_NODES) cnt[t] = 0.f;
    if (t <= NBUCK) bkcnt[t] = 0;
}

// ---------------- merged prep: W/Wid cvt+transpose | id multiplicity | bucket hist ----------------
__global__ __launch_bounds__(256) void k_prep(const float* __restrict__ W,
                                              const float* __restrict__ Wid,
                                              unsigned short* __restrict__ WtG,
                                              unsigned short* __restrict__ WidtG,
                                              const int* __restrict__ nid,
                                              float* __restrict__ cnt,
                                              const int* __restrict__ ei,
                                              int* __restrict__ bkcnt) {
    __shared__ int lcnt[NBUCK];
    const int b = blockIdx.x;
    const int tid = threadIdx.x;
    if (b < 128) {                       // cvt: 32768 elements
        const int t = b * 256 + tid;
        const int mat = t >> 14;
        const int r = t & 16383;
        const int k = r >> 6, c = r & 63;
        if (mat == 0) WtG[c * DIN + k] = f2bs(W[(long)k * C_OUT + c]);
        else          WidtG[c * DIN + k] = f2bs(Wid[(long)k * C_OUT + c]);
    } else if (b < 168) {                // cnt: 10000 ids
        const int t = (b - 128) * 256 + tid;
        if (t < NID_CNT) atomicAdd(&cnt[nid[t]], 1.0f);
    } else {                             // bhist: 391 blocks x 4096 edges
        for (int i = tid; i < NBUCK; i += 256) lcnt[i] = 0;
        __syncthreads();
        const int e0 = (b - 168) * 4096;
        #pragma unroll
        for (int j = 0; j < 16; ++j) {
            int e = e0 + j * 256 + tid;
            if (e < E_EDGES) atomicAdd(&lcnt[ei[E_EDGES + e] >> 8], 1);
        }
        __syncthreads();
        for (int i = tid; i < NBUCK; i += 256)
            if (lcnt[i]) atomicAdd(&bkcnt[i], lcnt[i]);
    }
}

// ---------------- CSR build: two-level counting sort ----------------

__global__ __launch_bounds__(512) void k_bscan(const int* __restrict__ bkcnt,
                                               int* __restrict__ bkoff,
                                               int* __restrict__ bkcur) {
    __shared__ int tmp[512];
    const int tid = threadIdx.x;
    const int v = (tid < NBUCK) ? bkcnt[tid] : 0;
    tmp[tid] = v;
    __syncthreads();
    for (int o = 1; o < 512; o <<= 1) {
        int t = (tid >= o) ? tmp[tid - o] : 0;
        __syncthreads();
        tmp[tid] += t;
        __syncthreads();
    }
    if (tid < NBUCK) {
        int excl = tmp[tid] - v;
        bkoff[tid] = excl;
        bkcur[tid] = excl;
        if (tid == NBUCK - 1) bkoff[NBUCK] = tmp[tid];
    }
}

__global__ __launch_bounds__(256) void k_bin(const int* __restrict__ ei,
                                             int* __restrict__ bkcur,
                                             int2* __restrict__ binned) {
    __shared__ int cnt[NBUCK];
    __shared__ int base[NBUCK];
    __shared__ int lcur[NBUCK];
    const int tid = threadIdx.x;
    for (int i = tid; i < NBUCK; i += 256) cnt[i] = 0;
    __syncthreads();
    const int e0 = blockIdx.x * 4096;
    int s[16], d[16];
    #pragma unroll
    for (int j = 0; j < 16; ++j) {
        int e = e0 + j * 256 + tid;
        if (e < E_EDGES) {
            s[j] = ei[e];
            d[j] = ei[E_EDGES + e];
            atomicAdd(&cnt[d[j] >> 8], 1);
        } else d[j] = -1;
    }
    __syncthreads();
    for (int i = tid; i < NBUCK; i += 256) {
        base[i] = cnt[i] ? atomicAdd(&bkcur[i], cnt[i]) : 0;
        lcur[i] = 0;
    }
    __syncthreads();
    #pragma unroll
    for (int j = 0; j < 16; ++j) {
        if (d[j] >= 0) {
            int b = d[j] >> 8;
            int r = atomicAdd(&lcur[b], 1);
            binned[base[b] + r] = make_int2(s[j], d[j]);
        }
    }
}

__global__ __launch_bounds__(256) void k_place(const int2* __restrict__ binned,
                                               const int* __restrict__ bkoff,
                                               int* __restrict__ csr,
                                               int* __restrict__ cur) {
    __shared__ int ncnt[256];
    __shared__ int tmp[256];
    __shared__ int ncur[256];
    const int tid = threadIdx.x;
    const int b = blockIdx.x;
    const int lo = bkoff[b], hi = bkoff[b + 1];
    const int node0 = b << 8;
    ncnt[tid] = 0;
    __syncthreads();
    for (int e = lo + tid; e < hi; e += 256)
        atomicAdd(&ncnt[binned[e].y - node0], 1);
    __syncthreads();
    const int v = ncnt[tid];
    tmp[tid] = v;
    __syncthreads();
    for (int o = 1; o < 256; o <<= 1) {
        int t = (tid >= o) ? tmp[tid - o] : 0;
        __syncthreads();
        tmp[tid] += t;
        __syncthreads();
    }
    const int incl = tmp[tid];
    if (node0 + tid < N_NODES) cur[node0 + tid] = lo + incl;  // inclusive end
    ncur[tid] = incl - v;
    __syncthreads();
    for (int e = lo + tid; e < hi; e += 256) {
        int2 p = binned[e];
        int r = atomicAdd(&ncur[p.y - node0], 1);
        csr[lo + r] = p.x;
    }
}

// ---------------- fused MFMA GEMM: h = x@W + cnt*(x@Wid); emits hb, ad, as ----------------
// 512 thr = 8 waves x 32 rows = 256 rows/block. W^T/Wid^T staged ONCE in LDS
// (swizzled); x streamed global->reg with DOUBLE-BUFFERED prefetch (static
// indices via full unroll) so >=4 float4 stay in flight under each step's MFMAs.
__global__ __launch_bounds__(512, 4) void k_gemm_fused(const float* __restrict__ x,
                                                       const unsigned short* __restrict__ WtG,
                                                       const unsigned short* __restrict__ WidtG,
                                                       const float* __restrict__ cnt,
                                                       const float* __restrict__ att,
                                                       __hip_bfloat16* __restrict__ hb,
                                                       float* __restrict__ ad,
                                                       float* __restrict__ as) {
    __shared__ __align__(16) char wlds[65536];  // wt [64c][512B] swz; wid at +32768; epilogue: hb tile [256][144B]
    __shared__ float cnt_lds[256];
    const int tid = threadIdx.x;
    const int w = tid >> 6, l = tid & 63;
    const int g = l >> 4, cl = l & 15;
    const int r0 = blockIdx.x * 256;

    #pragma unroll
    for (int i = 0; i < 4; ++i) {
        int f = tid + i * 512;     // 0..2047 chunks of 16B
        int c = f >> 5, s = f & 31;
        int byte = c * 512 + ((s ^ (c & 7)) << 4);
        *(bf16x8*)(wlds + byte)         = *(const bf16x8*)(WtG + (long)c * DIN + s * 8);
        *(bf16x8*)(wlds + 32768 + byte) = *(const bf16x8*)(WidtG + (long)c * DIN + s * 8);
    }
    if (tid < 256) cnt_lds[tid] = (r0 + tid < N_NODES) ? cnt[r0 + tid] : 0.f;
    __syncthreads();

    f32x4 acc1[2][4] = {};
    f32x4 acc2[2][4] = {};

    const int row0 = r0 + w * 32 + cl;
    const float* xp0 = x + (long)min(row0, N_NODES - 1) * DIN + g * 8;
    const float* xp1 = x + (long)min(row0 + 16, N_NODES - 1) * DIN + g * 8;

    // double-buffered x prefetch; xb indices are compile-time after full unroll
    float4 xb[2][4];
    xb[0][0] = *(const float4*)(xp0);
    xb[0][1] = *(const float4*)(xp0 + 4);
    xb[0][2] = *(const float4*)(xp1);
    xb[0][3] = *(const float4*)(xp1 + 4);
    #pragma unroll
    for (int kt = 0; kt < 8; ++kt) {
        if (kt < 7) {
            const int nb = (kt + 1) & 1;
            xb[nb][0] = *(const float4*)(xp0 + (kt + 1) * 32);
            xb[nb][1] = *(const float4*)(xp0 + (kt + 1) * 32 + 4);
            xb[nb][2] = *(const float4*)(xp1 + (kt + 1) * 32);
            xb[nb][3] = *(const float4*)(xp1 + (kt + 1) * 32 + 4);
        }
        const int cb = kt & 1;
        bf16x8 a0 = pack8(xb[cb][0], xb[cb][1]);
        bf16x8 a1 = pack8(xb[cb][2], xb[cb][3]);
        #pragma unroll
        for (int ct = 0; ct < 4; ++ct) {
            int c = ct * 16 + cl;
            int byte = c * 512 + (((kt * 4 + g) ^ (c & 7)) << 4);
            bf16x8 bw = *(const bf16x8*)(wlds + byte);
            bf16x8 bi = *(const bf16x8*)(wlds + 32768 + byte);
            acc1[0][ct] = __builtin_amdgcn_mfma_f32_16x16x32_bf16(a0, bw, acc1[0][ct], 0, 0, 0);
            acc1[1][ct] = __builtin_amdgcn_mfma_f32_16x16x32_bf16(a1, bw, acc1[1][ct], 0, 0, 0);
            acc2[0][ct] = __builtin_amdgcn_mfma_f32_16x16x32_bf16(a0, bi, acc2[0][ct], 0, 0, 0);
            acc2[1][ct] = __builtin_amdgcn_mfma_f32_16x16x32_bf16(a1, bi, acc2[1][ct], 0, 0, 0);
        }
    }
    __syncthreads();

    float attv1[4], attv2[4];
    #pragma unroll
    for (int ct = 0; ct < 4; ++ct) {
        attv1[ct] = att[ct * 16 + cl];
        attv2[ct] = att[C_OUT + ct * 16 + cl];
    }
    unsigned short* hbt = (unsigned short*)wlds;  // stride 72 elements (144 B)
    #pragma unroll
    for (int rt = 0; rt < 2; ++rt) {
        #pragma unroll
        for (int reg = 0; reg < 4; ++reg) {
            const int rbl = w * 32 + rt * 16 + g * 4 + reg;
            const float cv = cnt_lds[rbl];
            float pd = 0.f, ps = 0.f;
            #pragma unroll
            for (int ct = 0; ct < 4; ++ct) {
                float hv = acc1[rt][ct][reg] + cv * acc2[rt][ct][reg];
                pd += hv * attv1[ct];
                ps += hv * attv2[ct];
                hbt[rbl * 72 + ct * 16 + cl] = f2bs(hv);
            }
            #pragma unroll
            for (int o = 1; o < 16; o <<= 1) {
                pd += __shfl_xor(pd, o, 64);
                ps += __shfl_xor(ps, o, 64);
            }
            if (cl == 0) {
                int grow = r0 + rbl;
                if (grow < N_NODES) { ad[grow] = pd; as[grow] = ps; }
            }
        }
    }
    __syncthreads();
    #pragma unroll
    for (int i = 0; i < 4; ++i) {
        int f = tid + i * 512;
        int row = f >> 3, s = f & 7;
        int grow = r0 + row;
        if (grow < N_NODES) {
            bf16x8 v = *(const bf16x8*)(wlds + row * 144 + s * 16);
            *(bf16x8*)((unsigned short*)hb + (long)grow * C_OUT + s * 8) = v;
        }
    }
}

// ---------------- gather: 2 nodes/wave (32-lane groups), 2 channels/lane (bf16x2) ----------------
__global__ __launch_bounds__(256) void k_gather(const int* __restrict__ cur,
                                                const int* __restrict__ csr,
                                                const unsigned* __restrict__ hb2,
                                                const float* __restrict__ ad,
                                                const float* __restrict__ as,
                                                float* __restrict__ out) {
    const int lane = threadIdx.x & 63;
    const int lg = lane & 31;                  // lane in group
    const int gb = lane & 32;                  // group broadcast base
    const int i = blockIdx.x * 8 + ((threadIdx.x >> 6) << 1) + (lane >> 5);
    if (i >= N_NODES) return;
    const int end   = cur[i];
    const int start = (i > 0) ? cur[i - 1] : 0;
    const int deg   = end - start;
    const float adi = ad[i];
    const float asi = as[i];
    float2 acc;
    float den;
    if (deg <= 32) {
        int s = 0; float a = -1e30f;
        if (lg < deg) { s = csr[start + lg]; a = as[s]; }
        float mx = fmaxf(a, asi);
        #pragma unroll
        for (int o = 16; o > 0; o >>= 1) mx = fmaxf(mx, __shfl_xor(mx, o, 64));
        const float m = lrelu(adi + mx);
        float w = (lg < deg) ? __expf(lrelu(adi + a) - m) : 0.f;
        const float wself = __expf(lrelu(adi + asi) - m);
        float wsum = w;
        #pragma unroll
        for (int o = 16; o > 0; o >>= 1) wsum += __shfl_xor(wsum, o, 64);
        den = wself + wsum;
        float2 hv = unpk2(hb2[(long)i * 32 + lg]);
        acc = make_float2(wself * hv.x, wself * hv.y);
        int j = 0;
        for (; j + 4 <= deg; j += 4) {
            int   s0 = __shfl(s, gb + j, 64),     s1 = __shfl(s, gb + j + 1, 64),
                  s2 = __shfl(s, gb + j + 2, 64), s3 = __shfl(s, gb + j + 3, 64);
            float w0 = __shfl(w, gb + j, 64),     w1 = __shfl(w, gb + j + 1, 64),
                  w2 = __shfl(w, gb + j + 2, 64), w3 = __shfl(w, gb + j + 3, 64);
            float2 h0 = unpk2(hb2[(long)s0 * 32 + lg]);
            float2 h1 = unpk2(hb2[(long)s1 * 32 + lg]);
            float2 h2 = unpk2(hb2[(long)s2 * 32 + lg]);
            float2 h3 = unpk2(hb2[(long)s3 * 32 + lg]);
            acc.x += w0 * h0.x; acc.y += w0 * h0.y;
            acc.x += w1 * h1.x; acc.y += w1 * h1.y;
            acc.x += w2 * h2.x; acc.y += w2 * h2.y;
            acc.x += w3 * h3.x; acc.y += w3 * h3.y;
        }
        for (; j < deg; ++j) {
            int   sj = __shfl(s, gb + j, 64);
            float wj = __shfl(w, gb + j, 64);
            float2 hj = unpk2(hb2[(long)sj * 32 + lg]);
            acc.x += wj * hj.x; acc.y += wj * hj.y;
        }
    } else {  // rare: deg > 32
        float mx = asi;
        for (int b = 0; b < deg; b += 32) {
            int idx = b + lg;
            if (idx < deg) mx = fmaxf(mx, as[csr[start + idx]]);
        }
        #pragma unroll
        for (int o = 16; o > 0; o >>= 1) mx = fmaxf(mx, __shfl_xor(mx, o, 64));
        const float m = lrelu(adi + mx);
        const float wself = __expf(lrelu(adi + asi) - m);
        float2 hv = unpk2(hb2[(long)i * 32 + lg]);
        acc = make_float2(wself * hv.x, wself * hv.y);
        den = wself;
        for (int b = 0; b < deg; b += 32) {
            int idx = b + lg;
            int s = 0; float w = 0.f;
            if (idx < deg) {
                s = csr[start + idx];
                w = __expf(lrelu(adi + as[s]) - m);
            }
            const int cnt2 = min(32, deg - b);
            for (int j = 0; j < cnt2; ++j) {
                int   sj = __shfl(s, gb + j, 64);
                float wj = __shfl(w, gb + j, 64);
                float2 hj = unpk2(hb2[(long)sj * 32 + lg]);
                acc.x += wj * hj.x; acc.y += wj * hj.y;
            }
            float wsum = w;
            #pragma unroll
            for (int o = 16; o > 0; o >>= 1) wsum += __shfl_xor(wsum, o, 64);
            den += wsum;
        }
    }
    const float r = 1.f / (den + 1e-16f);
    *(float2*)(out + (long)i * C_OUT + lg * 2) = make_float2(acc.x * r, acc.y * r);
}

extern "C" void kernel_launch(void* const* d_in, const int* in_sizes, int n_in,
                              void* d_out, int out_size, void* d_ws, size_t ws_size,
                              hipStream_t stream) {
    const float* x   = (const float*)d_in[0];
    const int*   ei  = (const int*)d_in[1];
    const int*   nid = (const int*)d_in[2];
    const float* W   = (const float*)d_in[3];
    const float* Wid = (const float*)d_in[4];
    const float* att = (const float*)d_in[5];
    float* out = (float*)d_out;

    char* ws = (char*)d_ws;
    __hip_bfloat16* hb = (__hip_bfloat16*)(ws);      // 12,800,000 B
    int2*  binned = (int2*)(ws);                     // aliases hb; used only in CSR phase (before gemm)
    float* ad    = (float*)(ws + 12800000);          //    400,000 B
    float* as    = (float*)(ws + 13200000);          //    400,000 B
    int*   cur   = (int*)  (ws + 13600000);          //    400,000 B
    float* cnt   = (float*)(ws + 14000000);          //    400,000 B
    int*   csr   = (int*)  (ws + 14400000);          //  6,400,000 B
    unsigned short* WtG  = (unsigned short*)(ws + 20800000);  // 32,768 B
    unsigned short* WidG = (unsigned short*)(ws + 20832768);  // 32,768 B
    int*   bkcnt = (int*)  (ws + 20865536);          //  1,600 B
    int*   bkoff = (int*)  (ws + 20867200);          //  1,600 B
    int*   bkcur = (int*)  (ws + 20868800);          //  1,600 B

    // zero scratch
    k_zero<<<393, 256, 0, stream>>>(cnt, bkcnt);
    // merged prep: cvt (128 blocks) | id-count (40) | bucket hist (391)
    k_prep<<<559, 256, 0, stream>>>(W, Wid, WtG, WidG, nid, cnt, ei, bkcnt);
    k_bscan<<<1, 512, 0, stream>>>(bkcnt, bkoff, bkcur);
    k_bin<<<NBINBLK, 256, 0, stream>>>(ei, bkcur, binned);
    k_place<<<NBUCK, 256, 0, stream>>>(binned, bkoff, csr, cur);
    // fused feature path
    k_gemm_fused<<<GEMM_BLOCKS, 512, 0, stream>>>(x, WtG, WidG, cnt, att, hb, ad, as);
    k_gather<<<12500, 256, 0, stream>>>(cur, csr, (const unsigned*)hb, ad, as, out);
}